// Round 10
// baseline (255.738 us; speedup 1.0000x reference)
//
#include <hip/hip_runtime.h>
#include <hip/hip_bf16.h>

#define LL 4096
#define NH 16
#define DM 1024
#define DK 64
#define MTOT 8192
#define PI_F 3.14159265358979323846f

typedef short short8 __attribute__((ext_vector_type(8)));
typedef float f32x4 __attribute__((ext_vector_type(4)));

typedef __attribute__((address_space(1))) const unsigned char g_u8;
typedef __attribute__((address_space(3))) unsigned char l_u8;

__device__ __forceinline__ void gload16(const void* g, void* l){
  __builtin_amdgcn_global_load_lds((g_u8*)g, (l_u8*)l, 16, 0, 0);
}

__device__ __forceinline__ unsigned short f2bf(float x){
  union { float f; unsigned int u; } v; v.f = x;
  unsigned int r = v.u + 0x7FFFu + ((v.u >> 16) & 1u);
  return (unsigned short)(r >> 16);
}
__device__ __forceinline__ float bf2f(unsigned short u){
  union { unsigned int u; float f; } v; v.u = ((unsigned int)u) << 16; return v.f;
}

// ---------------- converts ----------------
__global__ void k_conv_x(const float* __restrict__ in, unsigned short* __restrict__ out, int n4){
  int i = blockIdx.x*256 + threadIdx.x;
  if (i >= n4) return;
  float4 v = ((const float4*)in)[i];
  ushort4 o; o.x=f2bf(v.x); o.y=f2bf(v.y); o.z=f2bf(v.z); o.w=f2bf(v.w);
  ((ushort4*)out)[i] = o;
}

// stacked split-convert: quads [0,n4) from q, [n4,2*n4) from k
__global__ void k_conv_x_split2(const float* __restrict__ q, const float* __restrict__ k,
                                unsigned short* __restrict__ hi, unsigned short* __restrict__ lo, int n4){
  int i = blockIdx.x*256 + threadIdx.x;
  float4 v = (i < n4) ? ((const float4*)q)[i] : ((const float4*)k)[i - n4];
  ushort4 oh, ol;
  oh.x=f2bf(v.x); ol.x=f2bf(v.x - bf2f(oh.x));
  oh.y=f2bf(v.y); ol.y=f2bf(v.y - bf2f(oh.y));
  oh.z=f2bf(v.z); ol.z=f2bf(v.z - bf2f(oh.z));
  oh.w=f2bf(v.w); ol.w=f2bf(v.w - bf2f(oh.w));
  ((ushort4*)hi)[i] = oh;
  ((ushort4*)lo)[i] = ol;
}

// fused: [0,n4) q-split, [n4,2n4) k-split, [2n4,3n4) value plain
__global__ void k_conv3(const float* __restrict__ q, const float* __restrict__ k,
                        const float* __restrict__ v,
                        unsigned short* __restrict__ hi, unsigned short* __restrict__ lo,
                        unsigned short* __restrict__ vout, int n4){
  int i = blockIdx.x*256 + threadIdx.x;
  if (i < 2*n4){
    float4 x = (i < n4) ? ((const float4*)q)[i] : ((const float4*)k)[i - n4];
    ushort4 oh, ol;
    oh.x=f2bf(x.x); ol.x=f2bf(x.x - bf2f(oh.x));
    oh.y=f2bf(x.y); ol.y=f2bf(x.y - bf2f(oh.y));
    oh.z=f2bf(x.z); ol.z=f2bf(x.z - bf2f(oh.z));
    oh.w=f2bf(x.w); ol.w=f2bf(x.w - bf2f(oh.w));
    ((ushort4*)hi)[i] = oh;
    ((ushort4*)lo)[i] = ol;
  } else {
    float4 x = ((const float4*)v)[i - 2*n4];
    ushort4 o; o.x=f2bf(x.x); o.y=f2bf(x.y); o.z=f2bf(x.z); o.w=f2bf(x.w);
    ((ushort4*)vout)[i - 2*n4] = o;
  }
}

// transpose-convert W [k][n] f32 -> Wt [n][k] bf16 (hi for all 4, lo for z<2)
__global__ void k_conv_wt(const float* __restrict__ W0, const float* __restrict__ W1,
                          const float* __restrict__ W2, const float* __restrict__ W3,
                          unsigned short* __restrict__ hi_base, unsigned short* __restrict__ lo_base){
  const float* W = (blockIdx.z==0)?W0:(blockIdx.z==1)?W1:(blockIdx.z==2)?W2:W3;
  unsigned short* oh = hi_base + (size_t)blockIdx.z*DM*DM;
  unsigned short* ol = (blockIdx.z<2) ? (lo_base + (size_t)blockIdx.z*DM*DM) : nullptr;
  __shared__ unsigned short th[64][65];
  __shared__ unsigned short tl[64][65];
  int n0 = blockIdx.x*64, k0 = blockIdx.y*64;
  for (int i=0;i<16;i++){
    int g = i*256 + threadIdx.x;
    int kr = g>>6, nc = g&63;
    float x = W[(size_t)(k0+kr)*DM + n0+nc];
    unsigned short h = f2bf(x);
    th[kr][nc] = h;
    tl[kr][nc] = f2bf(x - bf2f(h));
  }
  __syncthreads();
  for (int i=0;i<16;i++){
    int g = i*256 + threadIdx.x;
    int nr = g>>6, kc = g&63;
    oh[(size_t)(n0+nr)*DM + k0+kc] = th[kc][nr];
    if (ol) ol[(size_t)(n0+nr)*DM + k0+kc] = tl[kc][nr];
  }
}

// ---------------- plain bf16 GEMM (V projection, output projection) ----------------
// 128x128, BK=64, now double-buffered LDS (64KB, 2 blocks/CU at grid 512) with
// counted-vmcnt pipeline (round-6 pattern). XOR-swizzled LDS via pre-swizzled source.
template<int MODE>
__global__ __launch_bounds__(256) void k_gemm_plain(
    const short* __restrict__ A, const short* __restrict__ Bt,
    const float* __restrict__ bias, float* __restrict__ Cf, unsigned short* __restrict__ Cb)
{
  __shared__ short As[2][128][64];
  __shared__ short Bs[2][128][64];
  const int m0 = blockIdx.x*128, n0 = blockIdx.y*128;
  const int tid = threadIdx.x;
  const int wave = tid>>6, lane = tid&63;
  const int wm = (wave>>1)*64, wn = (wave&1)*64;
  const int li = lane&15, lk4 = lane>>4;
  const int srow = lane>>3;
  const int scol = (((lane&7) ^ srow))*8;   // pre-swizzled source chunk

  f32x4 acc[4][4] = {};

  auto STAGE = [&](int kt, int bufi){
    #pragma unroll
    for (int c=0;c<4;c++){
      int q = wave*4+c;
      int row = q*8 + srow;
      gload16(&A [(size_t)(m0+row)*DM + kt*64 + scol], &As[bufi][q*8][0]);
      gload16(&Bt[(size_t)(n0+row)*DM + kt*64 + scol], &Bs[bufi][q*8][0]);
    }
  };

  STAGE(0, 0);

  for (int kt=0; kt<16; ++kt){
    const int cur = kt&1;
    if (kt < 15){
      STAGE(kt+1, cur^1);
      asm volatile("s_waitcnt vmcnt(8)" ::: "memory");  // drain tile t's 8; t+1's 8 stay in flight
    } else {
      asm volatile("s_waitcnt vmcnt(0)" ::: "memory");
    }
    asm volatile("" ::: "memory");
    __builtin_amdgcn_s_barrier();
    asm volatile("" ::: "memory");

    #pragma unroll
    for (int kk=0; kk<64; kk+=32){
      short8 af[4], bfv[4];
      #pragma unroll
      for (int mi=0;mi<4;mi++)
        af[mi] = *(const short8*)&As[cur][wm+mi*16+li][((( (kk>>3)+lk4 ) ^ (li&7)))*8];
      #pragma unroll
      for (int ni=0;ni<4;ni++)
        bfv[ni] = *(const short8*)&Bs[cur][wn+ni*16+li][((( (kk>>3)+lk4 ) ^ (li&7)))*8];
      #pragma unroll
      for (int mi=0;mi<4;mi++)
        #pragma unroll
        for (int ni=0;ni<4;ni++)
          acc[mi][ni] = __builtin_amdgcn_mfma_f32_16x16x32_bf16(af[mi], bfv[ni], acc[mi][ni], 0,0,0);
    }
    asm volatile("" ::: "memory");
    __builtin_amdgcn_s_barrier();
    asm volatile("" ::: "memory");
  }
  #pragma unroll
  for (int mi=0;mi<4;mi++){
    #pragma unroll
    for (int ni=0;ni<4;ni++){
      const int col = n0 + wn + ni*16 + li;
      const float bv = bias[col];
      const int mbase = m0 + wm + mi*16 + lk4*4;
      #pragma unroll
      for (int r=0;r<4;r++){
        const int row = mbase + r;
        float v = acc[mi][ni][r] + bv;
        if (MODE==2){
          Cf[(size_t)row*DM + col] = v;
        } else {
          int b = row>>12, l = row&(LL-1), h = col>>6, d = col&63;
          Cb[(((size_t)(b*NH+h))*LL + l)*DK + d] = f2bf(v);
        }
      }
    }
  }
}

// ---------------- split-precision GEMM, 256x256 / 8 waves / wave-tile 128x64 ----------------
// FROZEN round-6 structure (109us): BK=32, dbuf LDS 128KB (grid 256 = 1/CU),
// counted-vmcnt pipeline, XOR-swizzled LDS via pre-swizzled source.
__global__ __launch_bounds__(512, 2) void k_gemm_split256(
    const short* __restrict__ Ahi, const short* __restrict__ Alo,
    const short* __restrict__ Whi, const short* __restrict__ Wlo,
    const float* __restrict__ bias_q, const float* __restrict__ bias_k,
    float* __restrict__ OutQ, float* __restrict__ OutK, int nq)
{
  __shared__ short AsH[2][256][32];
  __shared__ short AsL[2][256][32];
  __shared__ short BsH[2][256][32];
  __shared__ short BsL[2][256][32];

  const int side = (blockIdx.x >= nq) ? 1 : 0;
  const int m0 = blockIdx.x*256, n0 = blockIdx.y*256;
  const short* Bhi = Whi + (size_t)side*DM*DM;
  const short* Blo = Wlo + (size_t)side*DM*DM;
  const float* bias = side ? bias_k : bias_q;
  float* Ct = side ? OutK : OutQ;
  const int ml0 = m0 - side*(nq*256);

  const int tid = threadIdx.x;
  const int wave = tid>>6, lane = tid&63;
  const int wm = (wave>>2)*128;
  const int wn = (wave&3)*64;
  const int li = lane&15, lk4 = lane>>4;

  const int sr = lane>>2, sc4 = lane&3;
  const int scol = ((sc4 ^ (sr&3) ^ ((sr>>2)&3)))*8;
  const int rbyte = ((lk4 ^ (li&3) ^ (li>>2)))*8;

  f32x4 acc[8][4] = {};

  auto STAGE_HALF = [&](int kt, int bufi, int h){
    const int r0 = h*128 + wave*16;
    const int gr = r0 + sr;
    const int kof = kt*32 + scol;
    gload16(&Ahi[(size_t)(m0+gr)*DM + kof], &AsH[bufi][r0][0]);
    gload16(&Alo[(size_t)(m0+gr)*DM + kof], &AsL[bufi][r0][0]);
    gload16(&Bhi[(size_t)(n0+gr)*DM + kof], &BsH[bufi][r0][0]);
    gload16(&Blo[(size_t)(n0+gr)*DM + kof], &BsL[bufi][r0][0]);
  };

  STAGE_HALF(0, 0, 0);
  STAGE_HALF(0, 0, 1);

  for (int kt=0; kt<32; ++kt){
    const int cur = kt&1;
    if (kt < 31){
      STAGE_HALF(kt+1, cur^1, 0);
      asm volatile("s_waitcnt vmcnt(4)" ::: "memory");
    } else {
      asm volatile("s_waitcnt vmcnt(0)" ::: "memory");
    }
    asm volatile("" ::: "memory");
    __builtin_amdgcn_s_barrier();
    asm volatile("" ::: "memory");

    short8 bhf[4], blf[4];
    #pragma unroll
    for (int ni=0;ni<4;ni++){
      bhf[ni] = *(const short8*)&BsH[cur][wn+ni*16+li][rbyte];
      blf[ni] = *(const short8*)&BsL[cur][wn+ni*16+li][rbyte];
    }
    #pragma unroll
    for (int p=0;p<4;p++){
      if (p==2 && kt<31) STAGE_HALF(kt+1, cur^1, 1);
      short8 ah0 = *(const short8*)&AsH[cur][wm+(2*p  )*16+li][rbyte];
      short8 al0 = *(const short8*)&AsL[cur][wm+(2*p  )*16+li][rbyte];
      short8 ah1 = *(const short8*)&AsH[cur][wm+(2*p+1)*16+li][rbyte];
      short8 al1 = *(const short8*)&AsL[cur][wm+(2*p+1)*16+li][rbyte];
      __builtin_amdgcn_s_setprio(1);
      #pragma unroll
      for (int ni=0;ni<4;ni++){
        f32x4 a0 = acc[2*p][ni];
        a0 = __builtin_amdgcn_mfma_f32_16x16x32_bf16(ah0, bhf[ni], a0, 0,0,0);
        a0 = __builtin_amdgcn_mfma_f32_16x16x32_bf16(ah0, blf[ni], a0, 0,0,0);
        a0 = __builtin_amdgcn_mfma_f32_16x16x32_bf16(al0, bhf[ni], a0, 0,0,0);
        acc[2*p][ni] = a0;
        f32x4 a1 = acc[2*p+1][ni];
        a1 = __builtin_amdgcn_mfma_f32_16x16x32_bf16(ah1, bhf[ni], a1, 0,0,0);
        a1 = __builtin_amdgcn_mfma_f32_16x16x32_bf16(ah1, blf[ni], a1, 0,0,0);
        a1 = __builtin_amdgcn_mfma_f32_16x16x32_bf16(al1, bhf[ni], a1, 0,0,0);
        acc[2*p+1][ni] = a1;
      }
      __builtin_amdgcn_s_setprio(0);
    }
    asm volatile("" ::: "memory");
    __builtin_amdgcn_s_barrier();
    asm volatile("" ::: "memory");
  }

  #pragma unroll
  for (int mi=0;mi<8;mi++){
    #pragma unroll
    for (int ni=0;ni<4;ni++){
      const int col = n0 + wn + ni*16 + li;
      const float bv = bias[col];
      const int mbase = ml0 + wm + mi*16 + lk4*4;
      const int b = mbase>>12, l0 = mbase&(LL-1);
      const int h = col>>6, d = col&63;
      float4 o;
      o.x = acc[mi][ni][0]+bv; o.y = acc[mi][ni][1]+bv;
      o.z = acc[mi][ni][2]+bv; o.w = acc[mi][ni][3]+bv;
      *(float4*)&Ct[(((size_t)(b*NH+h))*DK + d)*LL + l0] = o;
    }
  }
}

// ---------------- radix-16 register FFT ----------------
__device__ __forceinline__ float2 cmul(float2 a, float2 b){
  return make_float2(a.x*b.x - a.y*b.y, a.x*b.y + a.y*b.x);
}
__device__ __forceinline__ int swz(int i){ return i ^ ((i>>4)&15); }

__device__ __forceinline__ float2 ctw(float2 v, int k, float sgn){
  float c, s;
  switch(k){
    case 0: return v;
    case 1: c= 0.92387953251f; s= 0.38268343236f; break;
    case 2: c= 0.70710678119f; s= 0.70710678119f; break;
    case 3: c= 0.38268343236f; s= 0.92387953251f; break;
    case 4: c= 0.f;            s= 1.f;            break;
    case 6: c=-0.70710678119f; s= 0.70710678119f; break;
    default:c=-0.92387953251f; s=-0.38268343236f; break; // k==9
  }
  s *= sgn;
  return make_float2(v.x*c - v.y*s, v.x*s + v.y*c);
}

template<int SGN>
__device__ __forceinline__ void dft16(float2 x[16]){
  const float sg = (float)SGN;
  #pragma unroll
  for (int m1=0;m1<4;m1++){
    float2 a=x[m1], b=x[m1+4], c=x[m1+8], d=x[m1+12];
    float acx=a.x+c.x, acy=a.y+c.y, sx=a.x-c.x, sy=a.y-c.y;
    float bdx=b.x+d.x, bdy=b.y+d.y, tx=b.x-d.x, ty=b.y-d.y;
    float ix=-sg*ty, iy=sg*tx;
    x[m1]    = make_float2(acx+bdx, acy+bdy);
    x[m1+4]  = make_float2(sx+ix,  sy+iy);
    x[m1+8]  = make_float2(acx-bdx, acy-bdy);
    x[m1+12] = make_float2(sx-ix,  sy-iy);
  }
  float2 y[16];
  #pragma unroll
  for (int p1=0;p1<4;p1++){
    float2 a = x[4*p1+0];
    float2 b = ctw(x[4*p1+1], p1,   sg);
    float2 c = ctw(x[4*p1+2], 2*p1, sg);
    float2 d = ctw(x[4*p1+3], 3*p1, sg);
    float acx=a.x+c.x, acy=a.y+c.y, sx=a.x-c.x, sy=a.y-c.y;
    float bdx=b.x+d.x, bdy=b.y+d.y, tx=b.x-d.x, ty=b.y-d.y;
    float ix=-sg*ty, iy=sg*tx;
    y[p1]    = make_float2(acx+bdx, acy+bdy);
    y[p1+4]  = make_float2(sx+ix,  sy+iy);
    y[p1+8]  = make_float2(acx-bdx, acy-bdy);
    y[p1+12] = make_float2(sx-ix,  sy-iy);
  }
  #pragma unroll
  for (int i=0;i<16;i++) x[i]=y[i];
}

template<int SGN>
__device__ __forceinline__ void twiddle_apply(float2 x[16], int j, float invden){
  float th = (float)SGN * 6.28318530717958647f * (float)j * invden;
  float s, c; __sincosf(th, &s, &c);
  float2 w1 = make_float2(c, s);
  float2 w2 = cmul(w1,w1), w3 = cmul(w2,w1), w4 = cmul(w2,w2);
  float2 w8 = cmul(w4,w4), w12 = cmul(w8,w4);
  float2 wl[4] = {make_float2(1.f,0.f), w1, w2, w3};
  float2 wh[4] = {make_float2(1.f,0.f), w4, w8, w12};
  #pragma unroll
  for (int m=1;m<16;m++){
    float2 tw = cmul(wh[m>>2], wl[m&3]);
    x[m] = cmul(x[m], tw);
  }
}

template<int SGN>
__device__ __forceinline__ void fft_stages(float2* lds, float2 x[16], int t){
  dft16<SGN>(x);
  #pragma unroll
  for (int p=0;p<16;p++) lds[swz(t*16+p)] = x[p];
  __syncthreads();
  #pragma unroll
  for (int m=0;m<16;m++) x[m] = lds[swz(t + 256*m)];
  __syncthreads();
  twiddle_apply<SGN>(x, t&15, 1.0f/256.0f);
  dft16<SGN>(x);
  {
    int base = (t>>4)*256 + (t&15);
    #pragma unroll
    for (int p=0;p<16;p++) lds[swz(base + 16*p)] = x[p];
  }
  __syncthreads();
  #pragma unroll
  for (int m=0;m<16;m++) x[m] = lds[swz(t + 256*m)];
  __syncthreads();
  twiddle_apply<SGN>(x, t, 1.0f/4096.0f);
  dft16<SGN>(x);
  #pragma unroll
  for (int p=0;p<16;p++) lds[swz(t + 256*p)] = x[p];
  __syncthreads();
}

// 1024 blocks: (bh, group of 2 d). Spart[bh][g][4096] float2 (32MB total).
__global__ __launch_bounds__(256) void k_fft_fwd(const float* __restrict__ Qt, const float* __restrict__ Kt,
                                                 float* __restrict__ Spart){
  __shared__ float2 lds[4096];
  const int bh = blockIdx.x >> 5, g = blockIdx.x & 31;
  const int t = threadIdx.x;
  float2 pacc[16];
  #pragma unroll
  for (int i=0;i<16;i++) pacc[i]=make_float2(0.f,0.f);
  for (int dd=0; dd<2; ++dd){
    const size_t base = ((size_t)bh*DK + g*2 + dd)*LL;
    float2 x[16];
    #pragma unroll
    for (int m=0;m<16;m++){
      int n = t + 256*m;
      x[m] = make_float2(Qt[base+n], Kt[base+n]);
    }
    fft_stages<-1>(lds, x, t);
    #pragma unroll
    for (int i=0;i<16;i++){
      int f = t + 256*i;
      float2 A = lds[swz(f)];
      float2 Bv = lds[swz((LL-f)&(LL-1))];
      float qr = 0.5f*(A.x+Bv.x), qi = 0.5f*(A.y-Bv.y);
      float kr = 0.5f*(A.y+Bv.y), ki = -0.5f*(A.x-Bv.x);
      pacc[i].x += qr*kr + qi*ki;
      pacc[i].y += qi*kr - qr*ki;
    }
    __syncthreads();
  }
  float2* Sp = (float2*)Spart + (size_t)blockIdx.x*LL;
  #pragma unroll
  for (int i=0;i<16;i++) Sp[t + 256*i] = pacc[i];
}

__global__ __launch_bounds__(256) void k_ifft_topk(const float* __restrict__ Spart,
                                                   float* __restrict__ w8, int* __restrict__ idx8){
  __shared__ float2 lds[4096];
  __shared__ float c[4096];
  __shared__ float rv[256];
  __shared__ int   ri[256];
  __shared__ float topv[8];
  __shared__ int   topi[8];
  const int bh = blockIdx.x, t = threadIdx.x;
  float2 x[16];
  #pragma unroll
  for (int m=0;m<16;m++){
    float2 acc = make_float2(0.f,0.f);
    int n = t + 256*m;
    for (int g2=0; g2<32; ++g2){
      float2 v = ((const float2*)Spart)[((size_t)bh*32+g2)*LL + n];
      acc.x += v.x; acc.y += v.y;
    }
    x[m] = acc;
  }
  fft_stages<1>(lds, x, t);
  const float scale = 1.0f/((float)LL * (float)DK);
  #pragma unroll
  for (int m=0;m<16;m++){ int f=t+256*m; c[f] = lds[swz(f)].x * scale; }
  __syncthreads();
  for (int kk=0; kk<8; kk++){
    float bv = -3.4e38f; int bi = 0;
    #pragma unroll
    for (int i=0;i<16;i++){
      int f = t + 256*i;
      float v = c[f];
      if (v > bv || (v == bv && f < bi)) { bv = v; bi = f; }
    }
    rv[t]=bv; ri[t]=bi;
    __syncthreads();
    for (int off=128; off>0; off>>=1){
      if (t < off){
        float ov = rv[t+off]; int oi = ri[t+off];
        if (ov > rv[t] || (ov == rv[t] && oi < ri[t])) { rv[t]=ov; ri[t]=oi; }
      }
      __syncthreads();
    }
    if (t==0){ topv[kk]=rv[0]; topi[kk]=ri[0]; c[ri[0]] = -3.0e38f; }
    __syncthreads();
  }
  if (t==0){
    float m = topv[0];
    float e[8], sum=0.f;
    for (int k=0;k<8;k++){ e[k]=__expf(topv[k]-m); sum+=e[k]; }
    for (int k=0;k<8;k++){ w8[bh*8+k]=e[k]/sum; idx8[bh*8+k]=topi[k]; }
  }
}

// ---------------- roll-gather (short8-vectorized) ----------------
__global__ __launch_bounds__(256) void k_gather(const unsigned short* __restrict__ Vh,
                                                const float* __restrict__ w8, const int* __restrict__ idx8,
                                                unsigned short* __restrict__ Ob){
  const int blk = blockIdx.x;
  const int bh = blk >> 6;
  const int l0 = (blk & 63) * 64;
  const int b = bh >> 4, h = bh & 15;
  float w[8]; int ix[8];
  #pragma unroll
  for (int k=0;k<8;k++){ w[k]=w8[bh*8+k]; ix[k]=idx8[bh*8+k]; }
  const int tid = threadIdx.x;
  const int d8 = (tid & 7) * 8;
  const int lrow = tid >> 3;
  #pragma unroll
  for (int it=0; it<2; ++it){
    const int l = l0 + it*32 + lrow;
    float acc[8] = {0,0,0,0,0,0,0,0};
    #pragma unroll
    for (int k=0;k<8;k++){
      const int sl = (l + ix[k]) & (LL-1);
      short8 v = *(const short8*)&Vh[((size_t)bh*LL + sl)*DK + d8];
      const float wk = w[k];
      #pragma unroll
      for (int j=0;j<8;j++)
        acc[j] += wk * bf2f((unsigned short)v[j]);
    }
    short8 o;
    #pragma unroll
    for (int j=0;j<8;j++) o[j] = (short)f2bf(acc[j]);
    *(short8*)&Ob[((size_t)(b*LL + l))*DM + h*DK + d8] = o;
  }
}

// ---------------- launch ----------------
extern "C" void kernel_launch(void* const* d_in, const int* in_sizes, int n_in,
                              void* d_out, int out_size, void* d_ws, size_t ws_size,
                              hipStream_t stream) {
  const float* query = (const float*)d_in[0];
  const float* key   = (const float*)d_in[1];
  const float* value = (const float*)d_in[2];
  const float* Wq = (const float*)d_in[3];
  const float* bq = (const float*)d_in[4];
  const float* Wk = (const float*)d_in[5];
  const float* bk = (const float*)d_in[6];
  const float* Wv = (const float*)d_in[7];
  const float* bv = (const float*)d_in[8];
  const float* Wo = (const float*)d_in[9];
  const float* bo = (const float*)d_in[10];
  float* out = (float*)d_out;

  char* ws = (char*)d_ws;
  const int n4 = MTOT*DM/4;
  const size_t MB16 = (size_t)MTOT*DM*2;   // 16 MiB

  size_t off = 0;
  auto take = [&](size_t b)->char*{ char* p = ws + off; off += (b + 255) & ~(size_t)255; return p; };

  const size_t tier2_bytes = 2*(2*MB16) + (size_t)4*DM*DM*2 + (size_t)2*DM*DM*2
                           + 2*((size_t)2*NH*DK*LL*4) + 16384;
  const size_t tier1_bytes = tier2_bytes + MB16;   // + dedicated Xv

  if (ws_size >= tier1_bytes) {
    // -------- tier 1: merged QK GEMM + fused converts --------
    short* Xs_hi = (short*)take(2*MB16);               // 32MB stacked [query;key] hi
    short* Xs_lo = (short*)take(2*MB16);               // 32MB stacked lo
    unsigned short* Xv = (unsigned short*)take(MB16);  // 16MB dedicated value bf16
    short* Wth = (short*)take((size_t)4*DM*DM*2);      // 8MB
    short* Wtl = (short*)take((size_t)2*DM*DM*2);      // 4MB
    float* Qt  = (float*)take((size_t)2*NH*DK*LL*4);   // 32MB [bh][d][l]
    float* Kt  = (float*)take((size_t)2*NH*DK*LL*4);   // 32MB
    float* w8  = (float*)take(32*8*4);
    int*  idx8 = (int*)take(32*8*4);
    // aliases on stacked buffers (dead after QK-GEMM):
    float* Spart = (float*)Xs_hi;                                   // 32MB (spans Xs_hi)
    unsigned short* Ob = (unsigned short*)((char*)Xs_hi + MB16);    // 16MB (after ifft)
    unsigned short* Vh = (unsigned short*)((char*)Xs_lo + MB16);    // 16MB

    k_conv_wt<<<dim3(16,16,4),256,0,stream>>>(Wq,Wk,Wv,Wo,(unsigned short*)Wth,(unsigned short*)Wtl);
    k_conv3<<<3*n4/256,256,0,stream>>>(query,key,value,
                                       (unsigned short*)Xs_hi,(unsigned short*)Xs_lo,Xv,n4);
    k_gemm_split256<<<dim3(64,4),512,0,stream>>>(Xs_hi, Xs_lo, Wth, Wtl, bq, bk, Qt, Kt, 32);
    k_gemm_plain<1><<<dim3(64,8),256,0,stream>>>((const short*)Xv, Wth + (size_t)2*DM*DM, bv, nullptr, Vh);
    k_fft_fwd<<<1024,256,0,stream>>>(Qt, Kt, Spart);
    k_ifft_topk<<<32,256,0,stream>>>(Spart, w8, idx8);
    k_gather<<<2048,256,0,stream>>>(Vh, w8, idx8, Ob);
    k_gemm_plain<2><<<dim3(64,8),256,0,stream>>>((const short*)Ob, Wth + (size_t)3*DM*DM, bo, out, nullptr);
  } else if (ws_size >= tier2_bytes) {
    // -------- tier 2: round-9 layout (QK merged, V convert after GEMM) --------
    short* Xs_hi = (short*)take(2*MB16);
    short* Xs_lo = (short*)take(2*MB16);
    short* Wth = (short*)take((size_t)4*DM*DM*2);
    short* Wtl = (short*)take((size_t)2*DM*DM*2);
    float* Qt  = (float*)take((size_t)2*NH*DK*LL*4);
    float* Kt  = (float*)take((size_t)2*NH*DK*LL*4);
    float* w8  = (float*)take(32*8*4);
    int*  idx8 = (int*)take(32*8*4);
    float* Spart = (float*)Xs_hi;                                   // 32MB spans Xs_hi
    unsigned short* Ob = (unsigned short*)((char*)Xs_hi + MB16);
    unsigned short* Xv = (unsigned short*)Xs_lo;
    unsigned short* Vh = (unsigned short*)((char*)Xs_lo + MB16);

    k_conv_wt<<<dim3(16,16,4),256,0,stream>>>(Wq,Wk,Wv,Wo,(unsigned short*)Wth,(unsigned short*)Wtl);
    k_conv_x_split2<<<2*n4/256,256,0,stream>>>(query,key,(unsigned short*)Xs_hi,(unsigned short*)Xs_lo,n4);
    k_gemm_split256<<<dim3(64,4),512,0,stream>>>(Xs_hi, Xs_lo, Wth, Wtl, bq, bk, Qt, Kt, 32);
    k_conv_x<<<n4/256,256,0,stream>>>(value, Xv, n4);
    k_gemm_plain<1><<<dim3(64,8),256,0,stream>>>((const short*)Xv, Wth + (size_t)2*DM*DM, bv, nullptr, Vh);
    k_fft_fwd<<<1024,256,0,stream>>>(Qt, Kt, Spart);
    k_ifft_topk<<<32,256,0,stream>>>(Spart, w8, idx8);
    k_gather<<<2048,256,0,stream>>>(Vh, w8, idx8, Ob);
    k_gemm_plain<2><<<dim3(64,8),256,0,stream>>>((const short*)Ob, Wth + (size_t)3*DM*DM, bo, out, nullptr);
  } else {
    // -------- tier 3: serialized fallback --------
    short* Xhi = (short*)take(MB16);
    short* Xlo = (short*)take(MB16);   // contiguous after Xhi: Spart spans both (32MB)
    short* Wth = (short*)take((size_t)4*DM*DM*2);
    short* Wtl = (short*)take((size_t)2*DM*DM*2);
    float* Qt  = (float*)take((size_t)2*NH*DK*LL*4);
    float* Kt  = (float*)take((size_t)2*NH*DK*LL*4);
    unsigned short* Vh = (unsigned short*)take((size_t)2*NH*LL*DK*2);
    float* w8  = (float*)take(32*8*4);
    int*  idx8 = (int*)take(32*8*4);
    float* Spart = (float*)Xhi;        // 32MB spanning Xhi+Xlo (both dead before fft)

    k_conv_wt<<<dim3(16,16,4),256,0,stream>>>(Wq,Wk,Wv,Wo,(unsigned short*)Wth,(unsigned short*)Wtl);

    k_conv_x_split2<<<n4/256,256,0,stream>>>(query,query,(unsigned short*)Xhi,(unsigned short*)Xlo,n4);
    k_gemm_split256<<<dim3(32,4),512,0,stream>>>(Xhi, Xlo, Wth, Wtl, bq, bq, Qt, Qt, 32);

    k_conv_x_split2<<<n4/256,256,0,stream>>>(key,key,(unsigned short*)Xhi,(unsigned short*)Xlo,n4);
    k_gemm_split256<<<dim3(32,4),512,0,stream>>>(Xhi, Xlo, Wth + (size_t)DM*DM, Wtl + (size_t)DM*DM,
                                                 bk, bk, Kt, Kt, 32);

    k_conv_x<<<n4/256,256,0,stream>>>(value,(unsigned short*)Xhi,n4);
    k_gemm_plain<1><<<dim3(64,8),256,0,stream>>>(Xhi, Wth + (size_t)2*DM*DM, bv, nullptr, Vh);

    k_fft_fwd<<<1024,256,0,stream>>>(Qt, Kt, Spart);
    k_ifft_topk<<<32,256,0,stream>>>(Spart, w8, idx8);
    k_gather<<<2048,256,0,stream>>>(Vh, w8, idx8, (unsigned short*)Xhi);

    k_gemm_plain<2><<<dim3(64,8),256,0,stream>>>(Xhi, Wth + (size_t)3*DM*DM, bo, out, nullptr);
  }
}

// Round 11
// 248.136 us; speedup vs baseline: 1.0306x; 1.0306x over previous
//
#include <hip/hip_runtime.h>
#include <hip/hip_bf16.h>

#define LL 4096
#define NH 16
#define DM 1024
#define DK 64
#define MTOT 8192
#define PI_F 3.14159265358979323846f

typedef short short8 __attribute__((ext_vector_type(8)));
typedef float f32x4 __attribute__((ext_vector_type(4)));

typedef __attribute__((address_space(1))) const unsigned char g_u8;
typedef __attribute__((address_space(3))) unsigned char l_u8;

__device__ __forceinline__ void gload16(const void* g, void* l){
  __builtin_amdgcn_global_load_lds((g_u8*)g, (l_u8*)l, 16, 0, 0);
}

__device__ __forceinline__ unsigned short f2bf(float x){
  union { float f; unsigned int u; } v; v.f = x;
  unsigned int r = v.u + 0x7FFFu + ((v.u >> 16) & 1u);
  return (unsigned short)(r >> 16);
}
__device__ __forceinline__ float bf2f(unsigned short u){
  union { unsigned int u; float f; } v; v.u = ((unsigned int)u) << 16; return v.f;
}

// ---------------- converts ----------------
__global__ void k_conv_x(const float* __restrict__ in, unsigned short* __restrict__ out, int n4){
  int i = blockIdx.x*256 + threadIdx.x;
  if (i >= n4) return;
  float4 v = ((const float4*)in)[i];
  ushort4 o; o.x=f2bf(v.x); o.y=f2bf(v.y); o.z=f2bf(v.z); o.w=f2bf(v.w);
  ((ushort4*)out)[i] = o;
}

// stacked split-convert: quads [0,n4) from q, [n4,2*n4) from k
__global__ void k_conv_x_split2(const float* __restrict__ q, const float* __restrict__ k,
                                unsigned short* __restrict__ hi, unsigned short* __restrict__ lo, int n4){
  int i = blockIdx.x*256 + threadIdx.x;
  float4 v = (i < n4) ? ((const float4*)q)[i] : ((const float4*)k)[i - n4];
  ushort4 oh, ol;
  oh.x=f2bf(v.x); ol.x=f2bf(v.x - bf2f(oh.x));
  oh.y=f2bf(v.y); ol.y=f2bf(v.y - bf2f(oh.y));
  oh.z=f2bf(v.z); ol.z=f2bf(v.z - bf2f(oh.z));
  oh.w=f2bf(v.w); ol.w=f2bf(v.w - bf2f(oh.w));
  ((ushort4*)hi)[i] = oh;
  ((ushort4*)lo)[i] = ol;
}

// transpose-convert W [k][n] f32 -> Wt [n][k] bf16 (hi for all 4, lo for z<2)
__global__ void k_conv_wt(const float* __restrict__ W0, const float* __restrict__ W1,
                          const float* __restrict__ W2, const float* __restrict__ W3,
                          unsigned short* __restrict__ hi_base, unsigned short* __restrict__ lo_base){
  const float* W = (blockIdx.z==0)?W0:(blockIdx.z==1)?W1:(blockIdx.z==2)?W2:W3;
  unsigned short* oh = hi_base + (size_t)blockIdx.z*DM*DM;
  unsigned short* ol = (blockIdx.z<2) ? (lo_base + (size_t)blockIdx.z*DM*DM) : nullptr;
  __shared__ unsigned short th[64][65];
  __shared__ unsigned short tl[64][65];
  int n0 = blockIdx.x*64, k0 = blockIdx.y*64;
  for (int i=0;i<16;i++){
    int g = i*256 + threadIdx.x;
    int kr = g>>6, nc = g&63;
    float x = W[(size_t)(k0+kr)*DM + n0+nc];
    unsigned short h = f2bf(x);
    th[kr][nc] = h;
    tl[kr][nc] = f2bf(x - bf2f(h));
  }
  __syncthreads();
  for (int i=0;i<16;i++){
    int g = i*256 + threadIdx.x;
    int nr = g>>6, kc = g&63;
    oh[(size_t)(n0+nr)*DM + k0+kc] = th[kc][nr];
    if (ol) ol[(size_t)(n0+nr)*DM + k0+kc] = tl[kc][nr];
  }
}

// ---------------- plain bf16 GEMM (V projection, output projection) ----------------
// LDS [128][64] (128B rows). XOR-swizzled: element (row, chunk c) stored at slot c^(row&7).
template<int MODE>
__global__ __launch_bounds__(256) void k_gemm_plain(
    const short* __restrict__ A, const short* __restrict__ Bt,
    const float* __restrict__ bias, float* __restrict__ Cf, unsigned short* __restrict__ Cb)
{
  __shared__ short As[128][64];
  __shared__ short Bs[128][64];
  const int m0 = blockIdx.x*128, n0 = blockIdx.y*128;
  const int tid = threadIdx.x;
  const int wave = tid>>6, lane = tid&63;
  const int wm = (wave>>1)*64, wn = (wave&1)*64;
  const int li = lane&15, lk4 = lane>>4;
  const int srow = lane>>3;
  const int scol = (((lane&7) ^ srow))*8;   // pre-swizzled source chunk
  f32x4 acc[4][4] = {};
  for (int kt=0; kt<16; ++kt){
    #pragma unroll
    for (int c=0;c<4;c++){
      int q = wave*4+c;
      int row = q*8 + srow;
      gload16(&A [(size_t)(m0+row)*DM + kt*64 + scol], &As[q*8][0]);
      gload16(&Bt[(size_t)(n0+row)*DM + kt*64 + scol], &Bs[q*8][0]);
    }
    __syncthreads();
    #pragma unroll
    for (int kk=0; kk<64; kk+=32){
      short8 af[4], bfv[4];
      #pragma unroll
      for (int mi=0;mi<4;mi++)
        af[mi] = *(const short8*)&As[wm+mi*16+li][((( (kk>>3)+lk4 ) ^ (li&7)))*8];
      #pragma unroll
      for (int ni=0;ni<4;ni++)
        bfv[ni] = *(const short8*)&Bs[wn+ni*16+li][((( (kk>>3)+lk4 ) ^ (li&7)))*8];
      #pragma unroll
      for (int mi=0;mi<4;mi++)
        #pragma unroll
        for (int ni=0;ni<4;ni++)
          acc[mi][ni] = __builtin_amdgcn_mfma_f32_16x16x32_bf16(af[mi], bfv[ni], acc[mi][ni], 0,0,0);
    }
    __syncthreads();
  }
  #pragma unroll
  for (int mi=0;mi<4;mi++){
    #pragma unroll
    for (int ni=0;ni<4;ni++){
      const int col = n0 + wn + ni*16 + li;
      const float bv = bias[col];
      const int mbase = m0 + wm + mi*16 + lk4*4;
      #pragma unroll
      for (int r=0;r<4;r++){
        const int row = mbase + r;
        float v = acc[mi][ni][r] + bv;
        if (MODE==2){
          Cf[(size_t)row*DM + col] = v;
        } else {
          int b = row>>12, l = row&(LL-1), h = col>>6, d = col&63;
          Cb[(((size_t)(b*NH+h))*LL + l)*DK + d] = f2bf(v);
        }
      }
    }
  }
}

// ---------------- split-precision GEMM, 256x256 / 8 waves / wave-tile 128x64 ----------------
// FROZEN round-6 structure: BK=32, dbuf LDS 128KB (grid 256 = 1/CU),
// counted-vmcnt pipeline (never drains in loop), XOR-swizzled LDS via pre-swizzled source.
__global__ __launch_bounds__(512, 2) void k_gemm_split256(
    const short* __restrict__ Ahi, const short* __restrict__ Alo,
    const short* __restrict__ Whi, const short* __restrict__ Wlo,
    const float* __restrict__ bias_q, const float* __restrict__ bias_k,
    float* __restrict__ OutQ, float* __restrict__ OutK, int nq)
{
  __shared__ short AsH[2][256][32];
  __shared__ short AsL[2][256][32];
  __shared__ short BsH[2][256][32];
  __shared__ short BsL[2][256][32];

  const int side = (blockIdx.x >= nq) ? 1 : 0;
  const int m0 = blockIdx.x*256, n0 = blockIdx.y*256;
  const short* Bhi = Whi + (size_t)side*DM*DM;
  const short* Blo = Wlo + (size_t)side*DM*DM;
  const float* bias = side ? bias_k : bias_q;
  float* Ct = side ? OutK : OutQ;
  const int ml0 = m0 - side*(nq*256);

  const int tid = threadIdx.x;
  const int wave = tid>>6, lane = tid&63;
  const int wm = (wave>>2)*128;     // 2 M-groups of 128
  const int wn = (wave&3)*64;       // 4 N-groups of 64
  const int li = lane&15, lk4 = lane>>4;

  // staging lane geometry: 16 rows x 4 slots per gload16; source chunk pre-swizzled
  const int sr = lane>>2, sc4 = lane&3;
  const int scol = ((sc4 ^ (sr&3) ^ ((sr>>2)&3)))*8;
  // read-side swizzled slot (static per lane; frag row-bases are %16==0)
  const int rbyte = ((lk4 ^ (li&3) ^ (li>>2)))*8;

  f32x4 acc[8][4] = {};

  // stage half h (rows h*128..h*128+127) of K-tile kt into buffer bufi: 4 loads/wave
  auto STAGE_HALF = [&](int kt, int bufi, int h){
    const int r0 = h*128 + wave*16;           // wave-uniform LDS base row
    const int gr = r0 + sr;                   // per-lane global row
    const int kof = kt*32 + scol;
    gload16(&Ahi[(size_t)(m0+gr)*DM + kof], &AsH[bufi][r0][0]);
    gload16(&Alo[(size_t)(m0+gr)*DM + kof], &AsL[bufi][r0][0]);
    gload16(&Bhi[(size_t)(n0+gr)*DM + kof], &BsH[bufi][r0][0]);
    gload16(&Blo[(size_t)(n0+gr)*DM + kof], &BsL[bufi][r0][0]);
  };

  // prologue: issue tile 0 (no drain; kt=0's vmcnt(4) covers it)
  STAGE_HALF(0, 0, 0);
  STAGE_HALF(0, 0, 1);

  for (int kt=0; kt<32; ++kt){
    const int cur = kt&1;
    // entry: issue next tile's half0, counted wait (this tile's 8 loads done,
    // next-h0's 4 may remain in flight), barrier.
    if (kt < 31){
      STAGE_HALF(kt+1, cur^1, 0);
      asm volatile("s_waitcnt vmcnt(4)" ::: "memory");
    } else {
      asm volatile("s_waitcnt vmcnt(0)" ::: "memory");
    }
    asm volatile("" ::: "memory");
    __builtin_amdgcn_s_barrier();
    asm volatile("" ::: "memory");

    // B fragments for the whole tile (8 swizzled reads)
    short8 bhf[4], blf[4];
    #pragma unroll
    for (int ni=0;ni<4;ni++){
      bhf[ni] = *(const short8*)&BsH[cur][wn+ni*16+li][rbyte];
      blf[ni] = *(const short8*)&BsL[cur][wn+ni*16+li][rbyte];
    }
    // 4 phases of {4 A-reads + 24 MFMA}; issue next tile's half1 mid-tile
    #pragma unroll
    for (int p=0;p<4;p++){
      if (p==2 && kt<31) STAGE_HALF(kt+1, cur^1, 1);
      short8 ah0 = *(const short8*)&AsH[cur][wm+(2*p  )*16+li][rbyte];
      short8 al0 = *(const short8*)&AsL[cur][wm+(2*p  )*16+li][rbyte];
      short8 ah1 = *(const short8*)&AsH[cur][wm+(2*p+1)*16+li][rbyte];
      short8 al1 = *(const short8*)&AsL[cur][wm+(2*p+1)*16+li][rbyte];
      __builtin_amdgcn_s_setprio(1);
      #pragma unroll
      for (int ni=0;ni<4;ni++){
        f32x4 a0 = acc[2*p][ni];
        a0 = __builtin_amdgcn_mfma_f32_16x16x32_bf16(ah0, bhf[ni], a0, 0,0,0);
        a0 = __builtin_amdgcn_mfma_f32_16x16x32_bf16(ah0, blf[ni], a0, 0,0,0);
        a0 = __builtin_amdgcn_mfma_f32_16x16x32_bf16(al0, bhf[ni], a0, 0,0,0);
        acc[2*p][ni] = a0;
        f32x4 a1 = acc[2*p+1][ni];
        a1 = __builtin_amdgcn_mfma_f32_16x16x32_bf16(ah1, bhf[ni], a1, 0,0,0);
        a1 = __builtin_amdgcn_mfma_f32_16x16x32_bf16(ah1, blf[ni], a1, 0,0,0);
        a1 = __builtin_amdgcn_mfma_f32_16x16x32_bf16(al1, bhf[ni], a1, 0,0,0);
        acc[2*p+1][ni] = a1;
      }
      __builtin_amdgcn_s_setprio(0);
    }
    // exit barrier: all waves done reading buf[cur] before anyone issues the
    // DMA (next iter entry) that will eventually overwrite it.
    asm volatile("" ::: "memory");
    __builtin_amdgcn_s_barrier();
    asm volatile("" ::: "memory");
  }

  // epilogue: Ct [b*NH+h][d][l] f32, float4 over l
  #pragma unroll
  for (int mi=0;mi<8;mi++){
    #pragma unroll
    for (int ni=0;ni<4;ni++){
      const int col = n0 + wn + ni*16 + li;
      const float bv = bias[col];
      const int mbase = ml0 + wm + mi*16 + lk4*4;
      const int b = mbase>>12, l0 = mbase&(LL-1);
      const int h = col>>6, d = col&63;
      float4 o;
      o.x = acc[mi][ni][0]+bv; o.y = acc[mi][ni][1]+bv;
      o.z = acc[mi][ni][2]+bv; o.w = acc[mi][ni][3]+bv;
      *(float4*)&Ct[(((size_t)(b*NH+h))*DK + d)*LL + l0] = o;
    }
  }
}

// ---------------- radix-16 register FFT ----------------
__device__ __forceinline__ float2 cmul(float2 a, float2 b){
  return make_float2(a.x*b.x - a.y*b.y, a.x*b.y + a.y*b.x);
}
__device__ __forceinline__ int swz(int i){ return i ^ ((i>>4)&15); }

__device__ __forceinline__ float2 ctw(float2 v, int k, float sgn){
  float c, s;
  switch(k){
    case 0: return v;
    case 1: c= 0.92387953251f; s= 0.38268343236f; break;
    case 2: c= 0.70710678119f; s= 0.70710678119f; break;
    case 3: c= 0.38268343236f; s= 0.92387953251f; break;
    case 4: c= 0.f;            s= 1.f;            break;
    case 6: c=-0.70710678119f; s= 0.70710678119f; break;
    default:c=-0.92387953251f; s=-0.38268343236f; break; // k==9
  }
  s *= sgn;
  return make_float2(v.x*c - v.y*s, v.x*s + v.y*c);
}

template<int SGN>
__device__ __forceinline__ void dft16(float2 x[16]){
  const float sg = (float)SGN;
  #pragma unroll
  for (int m1=0;m1<4;m1++){
    float2 a=x[m1], b=x[m1+4], c=x[m1+8], d=x[m1+12];
    float acx=a.x+c.x, acy=a.y+c.y, sx=a.x-c.x, sy=a.y-c.y;
    float bdx=b.x+d.x, bdy=b.y+d.y, tx=b.x-d.x, ty=b.y-d.y;
    float ix=-sg*ty, iy=sg*tx;
    x[m1]    = make_float2(acx+bdx, acy+bdy);
    x[m1+4]  = make_float2(sx+ix,  sy+iy);
    x[m1+8]  = make_float2(acx-bdx, acy-bdy);
    x[m1+12] = make_float2(sx-ix,  sy-iy);
  }
  float2 y[16];
  #pragma unroll
  for (int p1=0;p1<4;p1++){
    float2 a = x[4*p1+0];
    float2 b = ctw(x[4*p1+1], p1,   sg);
    float2 c = ctw(x[4*p1+2], 2*p1, sg);
    float2 d = ctw(x[4*p1+3], 3*p1, sg);
    float acx=a.x+c.x, acy=a.y+c.y, sx=a.x-c.x, sy=a.y-c.y;
    float bdx=b.x+d.x, bdy=b.y+d.y, tx=b.x-d.x, ty=b.y-d.y;
    float ix=-sg*ty, iy=sg*tx;
    y[p1]    = make_float2(acx+bdx, acy+bdy);
    y[p1+4]  = make_float2(sx+ix,  sy+iy);
    y[p1+8]  = make_float2(acx-bdx, acy-bdy);
    y[p1+12] = make_float2(sx-ix,  sy-iy);
  }
  #pragma unroll
  for (int i=0;i<16;i++) x[i]=y[i];
}

template<int SGN>
__device__ __forceinline__ void twiddle_apply(float2 x[16], int j, float invden){
  float th = (float)SGN * 6.28318530717958647f * (float)j * invden;
  float s, c; __sincosf(th, &s, &c);
  float2 w1 = make_float2(c, s);
  float2 w2 = cmul(w1,w1), w3 = cmul(w2,w1), w4 = cmul(w2,w2);
  float2 w8 = cmul(w4,w4), w12 = cmul(w8,w4);
  float2 wl[4] = {make_float2(1.f,0.f), w1, w2, w3};
  float2 wh[4] = {make_float2(1.f,0.f), w4, w8, w12};
  #pragma unroll
  for (int m=1;m<16;m++){
    float2 tw = cmul(wh[m>>2], wl[m&3]);
    x[m] = cmul(x[m], tw);
  }
}

template<int SGN>
__device__ __forceinline__ void fft_stages(float2* lds, float2 x[16], int t){
  dft16<SGN>(x);
  #pragma unroll
  for (int p=0;p<16;p++) lds[swz(t*16+p)] = x[p];
  __syncthreads();
  #pragma unroll
  for (int m=0;m<16;m++) x[m] = lds[swz(t + 256*m)];
  __syncthreads();
  twiddle_apply<SGN>(x, t&15, 1.0f/256.0f);
  dft16<SGN>(x);
  {
    int base = (t>>4)*256 + (t&15);
    #pragma unroll
    for (int p=0;p<16;p++) lds[swz(base + 16*p)] = x[p];
  }
  __syncthreads();
  #pragma unroll
  for (int m=0;m<16;m++) x[m] = lds[swz(t + 256*m)];
  __syncthreads();
  twiddle_apply<SGN>(x, t, 1.0f/4096.0f);
  dft16<SGN>(x);
  #pragma unroll
  for (int p=0;p<16;p++) lds[swz(t + 256*p)] = x[p];
  __syncthreads();
}

__global__ __launch_bounds__(256) void k_fft_fwd(const float* __restrict__ Qt, const float* __restrict__ Kt,
                                                 float* __restrict__ Spart){
  __shared__ float2 lds[4096];
  const int bh = blockIdx.x >> 4, g = blockIdx.x & 15;
  const int t = threadIdx.x;
  float2 pacc[16];
  #pragma unroll
  for (int i=0;i<16;i++) pacc[i]=make_float2(0.f,0.f);
  for (int dd=0; dd<4; ++dd){
    const size_t base = ((size_t)bh*DK + g*4 + dd)*LL;
    float2 x[16];
    #pragma unroll
    for (int m=0;m<16;m++){
      int n = t + 256*m;
      x[m] = make_float2(Qt[base+n], Kt[base+n]);
    }
    fft_stages<-1>(lds, x, t);
    #pragma unroll
    for (int i=0;i<16;i++){
      int f = t + 256*i;
      float2 A = lds[swz(f)];
      float2 Bv = lds[swz((LL-f)&(LL-1))];
      float qr = 0.5f*(A.x+Bv.x), qi = 0.5f*(A.y-Bv.y);
      float kr = 0.5f*(A.y+Bv.y), ki = -0.5f*(A.x-Bv.x);
      pacc[i].x += qr*kr + qi*ki;
      pacc[i].y += qi*kr - qr*ki;
    }
    __syncthreads();
  }
  float2* Sp = (float2*)Spart + (size_t)blockIdx.x*LL;
  #pragma unroll
  for (int i=0;i<16;i++) Sp[t + 256*i] = pacc[i];
}

__global__ __launch_bounds__(256) void k_ifft_topk(const float* __restrict__ Spart,
                                                   float* __restrict__ w8, int* __restrict__ idx8){
  __shared__ float2 lds[4096];
  __shared__ float c[4096];
  __shared__ float rv[256];
  __shared__ int   ri[256];
  __shared__ float topv[8];
  __shared__ int   topi[8];
  const int bh = blockIdx.x, t = threadIdx.x;
  float2 x[16];
  #pragma unroll
  for (int m=0;m<16;m++){
    float2 acc = make_float2(0.f,0.f);
    int n = t + 256*m;
    for (int g2=0; g2<16; ++g2){
      float2 v = ((const float2*)Spart)[((size_t)bh*16+g2)*LL + n];
      acc.x += v.x; acc.y += v.y;
    }
    x[m] = acc;
  }
  fft_stages<1>(lds, x, t);
  const float scale = 1.0f/((float)LL * (float)DK);
  #pragma unroll
  for (int m=0;m<16;m++){ int f=t+256*m; c[f] = lds[swz(f)].x * scale; }
  __syncthreads();
  for (int kk=0; kk<8; kk++){
    float bv = -3.4e38f; int bi = 0;
    #pragma unroll
    for (int i=0;i<16;i++){
      int f = t + 256*i;
      float v = c[f];
      if (v > bv || (v == bv && f < bi)) { bv = v; bi = f; }
    }
    rv[t]=bv; ri[t]=bi;
    __syncthreads();
    for (int off=128; off>0; off>>=1){
      if (t < off){
        float ov = rv[t+off]; int oi = ri[t+off];
        if (ov > rv[t] || (ov == rv[t] && oi < ri[t])) { rv[t]=ov; ri[t]=oi; }
      }
      __syncthreads();
    }
    if (t==0){ topv[kk]=rv[0]; topi[kk]=ri[0]; c[ri[0]] = -3.0e38f; }
    __syncthreads();
  }
  if (t==0){
    float m = topv[0];
    float e[8], sum=0.f;
    for (int k=0;k<8;k++){ e[k]=__expf(topv[k]-m); sum+=e[k]; }
    for (int k=0;k<8;k++){ w8[bh*8+k]=e[k]/sum; idx8[bh*8+k]=topi[k]; }
  }
}

// ---------------- roll-gather (short8-vectorized: 16B/lane loads+stores) ----------------
__global__ __launch_bounds__(256) void k_gather(const unsigned short* __restrict__ Vh,
                                                const float* __restrict__ w8, const int* __restrict__ idx8,
                                                unsigned short* __restrict__ Ob){
  const int blk = blockIdx.x;      // 2048 = 32 bh * 64 l-chunks
  const int bh = blk >> 6;
  const int l0 = (blk & 63) * 64;
  const int b = bh >> 4, h = bh & 15;
  float w[8]; int ix[8];
  #pragma unroll
  for (int k=0;k<8;k++){ w[k]=w8[bh*8+k]; ix[k]=idx8[bh*8+k]; }
  const int tid = threadIdx.x;
  const int d8 = (tid & 7) * 8;          // 8 d-values per lane, 8 lanes per row
  const int lrow = tid >> 3;             // 32 rows per iteration
  #pragma unroll
  for (int it=0; it<2; ++it){
    const int l = l0 + it*32 + lrow;
    float acc[8] = {0,0,0,0,0,0,0,0};
    #pragma unroll
    for (int k=0;k<8;k++){
      const int sl = (l + ix[k]) & (LL-1);
      short8 v = *(const short8*)&Vh[((size_t)bh*LL + sl)*DK + d8];
      const float wk = w[k];
      #pragma unroll
      for (int j=0;j<8;j++)
        acc[j] += wk * bf2f((unsigned short)v[j]);
    }
    short8 o;
    #pragma unroll
    for (int j=0;j<8;j++) o[j] = (short)f2bf(acc[j]);
    *(short8*)&Ob[((size_t)(b*LL + l))*DM + h*DK + d8] = o;
  }
}

// ---------------- launch ----------------
extern "C" void kernel_launch(void* const* d_in, const int* in_sizes, int n_in,
                              void* d_out, int out_size, void* d_ws, size_t ws_size,
                              hipStream_t stream) {
  const float* query = (const float*)d_in[0];
  const float* key   = (const float*)d_in[1];
  const float* value = (const float*)d_in[2];
  const float* Wq = (const float*)d_in[3];
  const float* bq = (const float*)d_in[4];
  const float* Wk = (const float*)d_in[5];
  const float* bk = (const float*)d_in[6];
  const float* Wv = (const float*)d_in[7];
  const float* bv = (const float*)d_in[8];
  const float* Wo = (const float*)d_in[9];
  const float* bo = (const float*)d_in[10];
  float* out = (float*)d_out;

  char* ws = (char*)d_ws;
  const int n4 = MTOT*DM/4;
  const size_t MB16 = (size_t)MTOT*DM*2;   // 16 MiB

  size_t off = 0;
  auto take = [&](size_t b)->char*{ char* p = ws + off; off += (b + 255) & ~(size_t)255; return p; };

  const size_t merged_bytes = 2*(2*MB16) + (size_t)4*DM*DM*2 + (size_t)2*DM*DM*2
                            + 2*((size_t)2*NH*DK*LL*4) + 16384;

  if (ws_size >= merged_bytes) {
    // -------- merged layout: Q+K projections stacked (M=16384, 256 blocks of 256 rows) --------
    short* Xs_hi = (short*)take(2*MB16);               // 32MB stacked [query;key] hi
    short* Xs_lo = (short*)take(2*MB16);               // 32MB stacked lo
    short* Wth = (short*)take((size_t)4*DM*DM*2);      // 8MB
    short* Wtl = (short*)take((size_t)2*DM*DM*2);      // 4MB
    float* Qt  = (float*)take((size_t)2*NH*DK*LL*4);   // 32MB [bh][d][l]
    float* Kt  = (float*)take((size_t)2*NH*DK*LL*4);   // 32MB
    float* w8  = (float*)take(32*8*4);
    int*  idx8 = (int*)take(32*8*4);
    // aliases on stacked buffers (dead after QK-GEMM):
    float* Spart = (float*)Xs_hi;                                   // 16MB
    unsigned short* Ob = (unsigned short*)((char*)Xs_hi + MB16);    // 16MB
    unsigned short* Xv = (unsigned short*)Xs_lo;                    // 16MB
    unsigned short* Vh = (unsigned short*)((char*)Xs_lo + MB16);    // 16MB

    k_conv_wt<<<dim3(16,16,4),256,0,stream>>>(Wq,Wk,Wv,Wo,(unsigned short*)Wth,(unsigned short*)Wtl);
    k_conv_x_split2<<<2*n4/256,256,0,stream>>>(query,key,(unsigned short*)Xs_hi,(unsigned short*)Xs_lo,n4);
    k_gemm_split256<<<dim3(64,4),512,0,stream>>>(Xs_hi, Xs_lo, Wth, Wtl, bq, bk, Qt, Kt, 32);
    k_conv_x<<<n4/256,256,0,stream>>>(value, Xv, n4);
    k_gemm_plain<1><<<dim3(64,8),256,0,stream>>>((const short*)Xv, Wth + (size_t)2*DM*DM, bv, nullptr, Vh);
    k_fft_fwd<<<512,256,0,stream>>>(Qt, Kt, Spart);
    k_ifft_topk<<<32,256,0,stream>>>(Spart, w8, idx8);
    k_gather<<<2048,256,0,stream>>>(Vh, w8, idx8, Ob);
    k_gemm_plain<2><<<dim3(64,8),256,0,stream>>>((const short*)Ob, Wth + (size_t)3*DM*DM, bo, out, nullptr);
  } else {
    // -------- fallback: serialized layout --------
    short* Xhi = (short*)take(MB16);
    short* Xlo = (short*)take(MB16);
    short* Wth = (short*)take((size_t)4*DM*DM*2);
    short* Wtl = (short*)take((size_t)2*DM*DM*2);
    float* Qt  = (float*)take((size_t)2*NH*DK*LL*4);
    float* Kt  = (float*)take((size_t)2*NH*DK*LL*4);
    unsigned short* Vh = (unsigned short*)take((size_t)2*NH*LL*DK*2);
    float* w8  = (float*)take(32*8*4);
    int*  idx8 = (int*)take(32*8*4);
    float* Spart = (float*)Xlo;

    k_conv_wt<<<dim3(16,16,4),256,0,stream>>>(Wq,Wk,Wv,Wo,(unsigned short*)Wth,(unsigned short*)Wtl);

    k_conv_x_split2<<<n4/256,256,0,stream>>>(query,query,(unsigned short*)Xhi,(unsigned short*)Xlo,n4);
    k_gemm_split256<<<dim3(32,4),512,0,stream>>>(Xhi, Xlo, Wth, Wtl, bq, bq, Qt, Qt, 32);

    k_conv_x_split2<<<n4/256,256,0,stream>>>(key,key,(unsigned short*)Xhi,(unsigned short*)Xlo,n4);
    k_gemm_split256<<<dim3(32,4),512,0,stream>>>(Xhi, Xlo, Wth + (size_t)DM*DM, Wtl + (size_t)DM*DM,
                                                 bk, bk, Kt, Kt, 32);

    k_conv_x<<<n4/256,256,0,stream>>>(value,(unsigned short*)Xhi,n4);
    k_gemm_plain<1><<<dim3(64,8),256,0,stream>>>(Xhi, Wth + (size_t)2*DM*DM, bv, nullptr, Vh);

    k_fft_fwd<<<512,256,0,stream>>>(Qt, Kt, Spart);
    k_ifft_topk<<<32,256,0,stream>>>(Spart, w8, idx8);
    k_gather<<<2048,256,0,stream>>>(Vh, w8, idx8, (unsigned short*)Xhi);

    k_gemm_plain<2><<<dim3(64,8),256,0,stream>>>(Xhi, Wth + (size_t)3*DM*DM, bo, out, nullptr);
  }
}